// Round 7
// baseline (420.967 us; speedup 1.0000x reference)
//
#include <hip/hip_runtime.h>

#define BN_EPS_F 1e-5f
#define MAXB 256          // max coarse buckets (node >> 9); n <= 131072
#define BSHIFT 9          // 512-node buckets
#define BIN_CHUNK 4096
#define BIN_EPT 16        // edges per thread in bin_kernel (256 thr * 16 = 4096)
#define NPART 400         // agg node partitions (grid = 8 * NPART)

typedef __attribute__((ext_vector_type(8))) short bf16x8;
typedef __attribute__((ext_vector_type(4))) float f32x4;

static __device__ __forceinline__ float bf2f(unsigned short u) {
  union { unsigned int i; float f; } c; c.i = ((unsigned int)u) << 16; return c.f;
}
static __device__ __forceinline__ unsigned short f2bf(float f) {
  union { float f; unsigned int i; } c; c.f = f;
  unsigned int r = c.i + 0x7FFFu + ((c.i >> 16) & 1u);
  return (unsigned short)(r >> 16);
}

// ---------------- k0: W (128x128 row-major [j][k]) -> B-fragment layout bf16 ----------------
__global__ void wfrag_kernel(const float* __restrict__ W, unsigned short* __restrict__ wfrag) {
  int idx = blockIdx.x * 256 + threadIdx.x;  // 0..16383
  int e = idx & 7, l = (idx >> 3) & 63, kk = (idx >> 9) & 3, jt = idx >> 11;
  int j = jt * 16 + (l & 15);
  int k = kk * 32 + ((l >> 4) << 3) + e;
  wfrag[idx] = f2bf(W[j * 128 + k]);
}

// ---------------- k1: h = x @ W.T + b -> bf16 h in TILED layout h[s][node][16] ----------------
// Block 256 thr = 4 waves; wave w computes rows [blk*64 + w*16, +16) x all 128 cols via MFMA.
__global__ __launch_bounds__(256) void linear_kernel(
    const float* __restrict__ x, const unsigned short* __restrict__ wfrag,
    const float* __restrict__ bias, unsigned short* __restrict__ ht, int n) {
  __shared__ unsigned short els[4][16 * 132];  // +4 pad to spread banks
  const int t = threadIdx.x;
  const int w = t >> 6, lane = t & 63;
  const int base = blockIdx.x * 64 + w * 16;
  const int row = base + (lane & 15);
  const int rowc = row < n ? row : (n - 1);
  const float4* xr = reinterpret_cast<const float4*>(x) + (size_t)rowc * 32;
  const bf16x8* bf = reinterpret_cast<const bf16x8*>(wfrag);

  f32x4 acc[8];
#pragma unroll
  for (int jt = 0; jt < 8; ++jt) acc[jt] = (f32x4){0.f, 0.f, 0.f, 0.f};

#pragma unroll
  for (int kk = 0; kk < 4; ++kk) {
    float4 lo = xr[kk * 8 + ((lane >> 4) << 1)];
    float4 hi = xr[kk * 8 + ((lane >> 4) << 1) + 1];
    bf16x8 a;
    a[0] = (short)f2bf(lo.x); a[1] = (short)f2bf(lo.y);
    a[2] = (short)f2bf(lo.z); a[3] = (short)f2bf(lo.w);
    a[4] = (short)f2bf(hi.x); a[5] = (short)f2bf(hi.y);
    a[6] = (short)f2bf(hi.z); a[7] = (short)f2bf(hi.w);
#pragma unroll
    for (int jt = 0; jt < 8; ++jt) {
      bf16x8 b = bf[(jt * 4 + kk) * 64 + lane];
      acc[jt] = __builtin_amdgcn_mfma_f32_16x16x32_bf16(a, b, acc[jt], 0, 0, 0);
    }
  }

  // Epilogue: bias add, bf16 pack to per-wave LDS, then tiled global stores.
  unsigned short* ep = els[w];
#pragma unroll
  for (int jt = 0; jt < 8; ++jt) {
    float bv = bias[jt * 16 + (lane & 15)];
#pragma unroll
    for (int r = 0; r < 4; ++r) {
      int orow = ((lane >> 4) << 2) + r;
      ep[orow * 132 + jt * 16 + (lane & 15)] = f2bf(acc[jt][r] + bv);
    }
  }
  // Per jt: 16 nodes x 16 feats = 512B contiguous in tiled layout.
  const int nl = lane >> 2;           // node_local 0..15
  const int f4 = (lane & 3) << 2;     // feature start within slice
  const int gnode = base + nl;
#pragma unroll
  for (int jt = 0; jt < 8; ++jt) {
    if (gnode < n) {
      ushort4 v = *reinterpret_cast<const ushort4*>(&ep[nl * 132 + jt * 16 + f4]);
      *reinterpret_cast<ushort4*>(&ht[((size_t)jt * n + gnode) * 16 + f4]) = v;
    }
  }
}

// ---------------- k2: coarse bucket histogram (bucket = row >> BSHIFT) ----------------
__global__ __launch_bounds__(256) void bucket_hist_kernel(
    const int* __restrict__ row, int* __restrict__ bhist, int e_total, int nb) {
  __shared__ int bh[MAXB];
  const int t = threadIdx.x;
  bh[t] = 0;
  __syncthreads();
  int i = blockIdx.x * 256 + t;
  const int stride = gridDim.x * 256;
  for (; i < e_total; i += stride) atomicAdd(&bh[row[i] >> BSHIFT], 1);
  __syncthreads();
  if (t < nb) {
    int c = bh[t];
    if (c) atomicAdd(&bhist[t], c);
  }
}

// ---------------- k3: exclusive scan of bucket hist -> bbase, bcursor ----------------
__global__ void bucket_scan_kernel(const int* __restrict__ bhist, int* __restrict__ bbase,
                                   int* __restrict__ bcursor, int nb, int e_total) {
  __shared__ int sd[MAXB];
  const int t = threadIdx.x;  // MAXB
  int v = (t < nb) ? bhist[t] : 0;
  sd[t] = v;
  __syncthreads();
  for (int off = 1; off < MAXB; off <<= 1) {
    int u = (t >= off) ? sd[t - off] : 0;
    __syncthreads();
    sd[t] += u;
    __syncthreads();
  }
  int excl = sd[t] - v;
  if (t < nb) { bbase[t] = excl; bcursor[t] = excl; }
  if (t == 0) bbase[nb] = e_total;
}

// ---------------- k4: bin edges into coarse buckets, packed (lr<<17)|col ----------------
__global__ __launch_bounds__(256) void bin_kernel(
    const int* __restrict__ row, const int* __restrict__ col,
    int* __restrict__ bcursor, unsigned int* __restrict__ pairs, int e_total, int nb) {
  __shared__ int scount[MAXB];
  __shared__ int gbase[MAXB];
  const int t = threadIdx.x;
  scount[t] = 0;
  __syncthreads();
  const int base = blockIdx.x * BIN_CHUNK;
  int bkt[BIN_EPT], slot[BIN_EPT];
  unsigned int pk[BIN_EPT];
#pragma unroll
  for (int k = 0; k < BIN_EPT; ++k) {
    int i = base + t + (k << 8);
    bkt[k] = -1;
    if (i < e_total) {
      int r = row[i], c = col[i];
      bkt[k] = r >> BSHIFT;
      pk[k] = ((unsigned int)(r & ((1 << BSHIFT) - 1)) << 17) | (unsigned int)c;
      slot[k] = atomicAdd(&scount[bkt[k]], 1);
    }
  }
  __syncthreads();
  if (t < nb) {
    int c = scount[t];
    gbase[t] = c ? atomicAdd(&bcursor[t], c) : 0;
  }
  __syncthreads();
#pragma unroll
  for (int k = 0; k < BIN_EPT; ++k) {
    if (bkt[k] >= 0) pairs[gbase[bkt[k]] + slot[k]] = pk[k];
  }
}

// ---------------- k5: per-bucket CSR build (rowptr + scol), L2-local ----------------
__global__ __launch_bounds__(256) void csr_kernel(
    const unsigned int* __restrict__ pairs, const int* __restrict__ bbase,
    int* __restrict__ rowptr, int* __restrict__ scol, int n, int e_total) {
  __shared__ int lh[1 << BSHIFT];
  __shared__ int sscan[256];
  const int b = blockIdx.x;
  const int t = threadIdx.x;
  const int node_base = b << BSHIFT;
  const int nn = min(1 << BSHIFT, n - node_base);
  const int p0 = bbase[b], p1 = bbase[b + 1];
  for (int j = t; j < (1 << BSHIFT); j += 256) lh[j] = 0;
  __syncthreads();
  for (int i = p0 + t; i < p1; i += 256) {
    atomicAdd(&lh[pairs[i] >> 17], 1);
  }
  __syncthreads();
  const int v0 = lh[2 * t + 0], v1 = lh[2 * t + 1];
  const int s = v0 + v1;
  sscan[t] = s;
  __syncthreads();
  for (int off = 1; off < 256; off <<= 1) {
    int u = (t >= off) ? sscan[t - off] : 0;
    __syncthreads();
    sscan[t] += u;
    __syncthreads();
  }
  const int excl = sscan[t] - s;
  const int c0 = excl, c1 = excl + v0;
  if (2 * t + 0 < nn) rowptr[node_base + 2 * t + 0] = p0 + c0;
  if (2 * t + 1 < nn) rowptr[node_base + 2 * t + 1] = p0 + c1;
  __syncthreads();
  lh[2 * t + 0] = c0; lh[2 * t + 1] = c1;
  __syncthreads();
  for (int i = p0 + t; i < p1; i += 256) {
    unsigned int p = pairs[i];
    int pl = atomicAdd(&lh[p >> 17], 1);
    scol[p0 + pl] = (int)(p & 0x1FFFFu);
  }
  if (b == 0 && t == 0) rowptr[n] = e_total;
}

// ---------------- k6: feature-sliced mean-agg; slice = blockIdx & 7 -> XCD affinity ----------
// Wave per node; 8 edge-groups (g=lane>>3) x 8 feature-pairs (f=lane&7, ushort2 = 32B/row-slice).
__global__ __launch_bounds__(256) void agg_kernel(
    const ushort2* __restrict__ ht2, const int* __restrict__ rowptr,
    const int* __restrict__ scol, unsigned short* __restrict__ outp,
    float* __restrict__ stat_sum, float* __restrict__ stat_sumsq, int n, int npp) {
  const int t = threadIdx.x;
  const int wave = t >> 6, lane = t & 63;
  const int s = blockIdx.x & 7;
  const int part = blockIdx.x >> 3;
  const int f = lane & 7, g = lane >> 3;
  const size_t sn = (size_t)s * n;
  const int start = part * npp;
  const int end = min(n, start + npp);
  ushort2* op2 = reinterpret_cast<ushort2*>(outp);
  float ls0 = 0.f, ls1 = 0.f, lq0 = 0.f, lq1 = 0.f;
  for (int node = start + wave; node < end; node += 4) {
    const int r0 = rowptr[node], r1 = rowptr[node + 1];
    float a0 = 0.f, a1 = 0.f;
    for (int e = r0 + g; e < r1; e += 8) {
      int c = scol[e];
      ushort2 v = ht2[(sn + c) * 8 + f];
      a0 += bf2f(v.x); a1 += bf2f(v.y);
    }
    a0 += __shfl_xor(a0, 8, 64); a1 += __shfl_xor(a1, 8, 64);
    a0 += __shfl_xor(a0, 16, 64); a1 += __shfl_xor(a1, 16, 64);
    a0 += __shfl_xor(a0, 32, 64); a1 += __shfl_xor(a1, 32, 64);
    if (g == 0) {
      ushort2 hv = ht2[(sn + node) * 8 + f];
      const float inv = 1.0f / ((float)(r1 - r0) + 1e-8f);
      float v0 = fmaf(a0, inv, bf2f(hv.x));
      float v1 = fmaf(a1, inv, bf2f(hv.y));
      ushort2 o; o.x = f2bf(v0); o.y = f2bf(v1);
      op2[(sn + node) * 8 + f] = o;
      ls0 += v0; ls1 += v1;
      lq0 = fmaf(v0, v0, lq0); lq1 = fmaf(v1, v1, lq1);
    }
  }
  __shared__ float rs[4][16], rq[4][16];
  if (g == 0) {
    rs[wave][2 * f] = ls0; rs[wave][2 * f + 1] = ls1;
    rq[wave][2 * f] = lq0; rq[wave][2 * f + 1] = lq1;
  }
  __syncthreads();
  if (t < 16) {
    float sv = rs[0][t] + rs[1][t] + rs[2][t] + rs[3][t];
    float qv = rq[0][t] + rq[1][t] + rq[2][t] + rq[3][t];
    atomicAdd(&stat_sum[s * 16 + t], sv);
    atomicAdd(&stat_sumsq[s * 16 + t], qv);
  }
}

// ---------------- k7: BN stats -> per-feature scale/shift ----------------
__global__ void finalize_kernel(const float* __restrict__ ssum, const float* __restrict__ ssq,
                                const float* __restrict__ gamma, const float* __restrict__ beta,
                                float* __restrict__ scale, float* __restrict__ shift, int n) {
  const int t = threadIdx.x;  // 128
  const float invn = 1.0f / (float)n;
  float mean = ssum[t] * invn;
  float var = ssq[t] * invn - mean * mean;
  float sc = gamma[t] * rsqrtf(var + BN_EPS_F);
  scale[t] = sc;
  shift[t] = beta[t] - mean * sc;
}

// ---------------- k8: BN apply — read tiled bf16 pre-BN, write fp32 d_out rows ----------------
__global__ __launch_bounds__(256) void bn_kernel(const unsigned short* __restrict__ outp,
                                                 float* __restrict__ out,
                                                 const float* __restrict__ scale,
                                                 const float* __restrict__ shift, int n_nodes) {
  __shared__ float sc[128], sh[128];
  if (threadIdx.x < 128) {
    sc[threadIdx.x] = scale[threadIdx.x];
    sh[threadIdx.x] = shift[threadIdx.x];
  }
  __syncthreads();
  const ushort4* op4 = reinterpret_cast<const ushort4*>(outp);
  const int total4 = n_nodes * 32;
  int i = blockIdx.x * 256 + threadIdx.x;
  const int stride = gridDim.x * 256;
  float4* o4 = reinterpret_cast<float4*>(out);
  for (; i < total4; i += stride) {
    const int node = i >> 5, fq4 = i & 31;
    const int slice = fq4 >> 2;
    ushort4 v = op4[((size_t)slice * n_nodes + node) * 4 + (fq4 & 3)];
    const int fq = fq4 << 2;
    float4 r;
    r.x = fmaf(bf2f(v.x), sc[fq + 0], sh[fq + 0]);
    r.y = fmaf(bf2f(v.y), sc[fq + 1], sh[fq + 1]);
    r.z = fmaf(bf2f(v.z), sc[fq + 2], sh[fq + 2]);
    r.w = fmaf(bf2f(v.w), sc[fq + 3], sh[fq + 3]);
    o4[i] = r;
  }
}

extern "C" void kernel_launch(void* const* d_in, const int* in_sizes, int n_in,
                              void* d_out, int out_size, void* d_ws, size_t ws_size,
                              hipStream_t stream) {
  const float* x     = (const float*)d_in[0];
  const int*   ei    = (const int*)d_in[1];
  const float* W     = (const float*)d_in[2];
  const float* bias  = (const float*)d_in[3];
  const float* gamma = (const float*)d_in[4];
  const float* beta  = (const float*)d_in[5];
  const int n = in_sizes[0] / 128;   // 100000
  const int e = in_sizes[1] / 2;     // 1600000
  const int* row = ei;
  const int* col = ei + e;
  float* out = (float*)d_out;

  char* base = (char*)d_ws;
  size_t off = 0;
  auto carve = [&](size_t bytes) -> char* {
    char* p = base + off;
    off += (bytes + 255) & ~(size_t)255;
    return p;
  };
  unsigned short* ht   = (unsigned short*)carve((size_t)n * 128 * 2);  // 25.6 MB tiled h
  unsigned short* outp = (unsigned short*)carve((size_t)n * 128 * 2);  // 25.6 MB tiled pre-BN
  unsigned short* wfrag = (unsigned short*)carve(128 * 128 * 2);       // 32 KB
  unsigned int* pairs = (unsigned int*)carve((size_t)e * 4);           // 6.4 MB
  int*   scol     = (int*)carve((size_t)e * 4);                        // 6.4 MB
  int*   rowptr   = (int*)carve((size_t)(n + 1) * 4);
  int*   bcursor  = (int*)carve(MAXB * 4);
  int*   bbase    = (int*)carve((MAXB + 1) * 4);
  float* scale    = (float*)carve(512);
  float* shift    = (float*)carve(512);
  char*  zbase    = base + off;
  int*   bhist    = (int*)carve(MAXB * 4);
  float* ssum     = (float*)carve(512);
  float* ssq      = (float*)carve(512);
  size_t zlen     = (size_t)((base + off) - zbase);
  (void)ws_size; (void)n_in; (void)out_size;

  const int nb = (n + (1 << BSHIFT) - 1) >> BSHIFT;      // 196 (<= MAXB required)
  const int bin_grid = (e + BIN_CHUNK - 1) / BIN_CHUNK;  // 391
  const int lin_grid = (n + 63) / 64;                    // 1563
  const int npp = (n + NPART - 1) / NPART;               // 250

  hipMemsetAsync(zbase, 0, zlen, stream);
  wfrag_kernel<<<64, 256, 0, stream>>>(W, wfrag);
  linear_kernel<<<lin_grid, 256, 0, stream>>>(x, wfrag, bias, ht, n);
  bucket_hist_kernel<<<256, 256, 0, stream>>>(row, bhist, e, nb);
  bucket_scan_kernel<<<1, MAXB, 0, stream>>>(bhist, bbase, bcursor, nb, e);
  bin_kernel<<<bin_grid, 256, 0, stream>>>(row, col, bcursor, pairs, e, nb);
  csr_kernel<<<nb, 256, 0, stream>>>(pairs, bbase, rowptr, scol, n, e);
  agg_kernel<<<8 * NPART, 256, 0, stream>>>((const ushort2*)ht, rowptr, scol, outp, ssum, ssq, n, npp);
  finalize_kernel<<<1, 128, 0, stream>>>(ssum, ssq, gamma, beta, scale, shift, n);
  bn_kernel<<<2048, 256, 0, stream>>>(outp, out, scale, shift, n);
}

// Round 10
// 328.292 us; speedup vs baseline: 1.2823x; 1.2823x over previous
//
#include <hip/hip_runtime.h>

#define BN_EPS_F 1e-5f
#define MAXB 256          // max coarse buckets (node >> 9); n <= 131072
#define BSHIFT 9          // 512-node buckets
#define BIN_CHUNK 4096
#define BIN_EPT 16        // edges per thread in bin_kernel (256 thr * 16 = 4096)
#define NPART 400         // agg node partitions (grid = 8 * NPART)

typedef __attribute__((ext_vector_type(8))) short bf16x8;
typedef __attribute__((ext_vector_type(4))) float f32x4;

static __device__ __forceinline__ float bf2f(unsigned short u) {
  union { unsigned int i; float f; } c; c.i = ((unsigned int)u) << 16; return c.f;
}
static __device__ __forceinline__ unsigned short f2bf(float f) {
  union { float f; unsigned int i; } c; c.f = f;
  unsigned int r = c.i + 0x7FFFu + ((c.i >> 16) & 1u);
  return (unsigned short)(r >> 16);
}

// ---------------- k0: W (128x128 row-major [j][k]) -> B-fragment layout bf16 ----------------
__global__ void wfrag_kernel(const float* __restrict__ W, unsigned short* __restrict__ wfrag) {
  int idx = blockIdx.x * 256 + threadIdx.x;  // 0..16383
  int e = idx & 7, l = (idx >> 3) & 63, kk = (idx >> 9) & 3, jt = idx >> 11;
  int j = jt * 16 + (l & 15);
  int k = kk * 32 + ((l >> 4) << 3) + e;
  wfrag[idx] = f2bf(W[j * 128 + k]);
}

// ---------------- k1: h = x @ W.T + b -> bf16 h in TILED layout h[s][node][16] ----------------
__global__ __launch_bounds__(256) void linear_kernel(
    const float* __restrict__ x, const unsigned short* __restrict__ wfrag,
    const float* __restrict__ bias, unsigned short* __restrict__ ht, int n) {
  __shared__ unsigned short els[4][16 * 132];  // +4 pad to spread banks
  const int t = threadIdx.x;
  const int w = t >> 6, lane = t & 63;
  const int base = blockIdx.x * 64 + w * 16;
  const int row = base + (lane & 15);
  const int rowc = row < n ? row : (n - 1);
  const float4* xr = reinterpret_cast<const float4*>(x) + (size_t)rowc * 32;
  const bf16x8* bf = reinterpret_cast<const bf16x8*>(wfrag);

  f32x4 acc[8];
#pragma unroll
  for (int jt = 0; jt < 8; ++jt) acc[jt] = (f32x4){0.f, 0.f, 0.f, 0.f};

#pragma unroll
  for (int kk = 0; kk < 4; ++kk) {
    float4 lo = xr[kk * 8 + ((lane >> 4) << 1)];
    float4 hi = xr[kk * 8 + ((lane >> 4) << 1) + 1];
    bf16x8 a;
    a[0] = (short)f2bf(lo.x); a[1] = (short)f2bf(lo.y);
    a[2] = (short)f2bf(lo.z); a[3] = (short)f2bf(lo.w);
    a[4] = (short)f2bf(hi.x); a[5] = (short)f2bf(hi.y);
    a[6] = (short)f2bf(hi.z); a[7] = (short)f2bf(hi.w);
#pragma unroll
    for (int jt = 0; jt < 8; ++jt) {
      bf16x8 b = bf[(jt * 4 + kk) * 64 + lane];
      acc[jt] = __builtin_amdgcn_mfma_f32_16x16x32_bf16(a, b, acc[jt], 0, 0, 0);
    }
  }

  unsigned short* ep = els[w];
#pragma unroll
  for (int jt = 0; jt < 8; ++jt) {
    float bv = bias[jt * 16 + (lane & 15)];
#pragma unroll
    for (int r = 0; r < 4; ++r) {
      int orow = ((lane >> 4) << 2) + r;
      ep[orow * 132 + jt * 16 + (lane & 15)] = f2bf(acc[jt][r] + bv);
    }
  }
  const int nl = lane >> 2;           // node_local 0..15
  const int f4 = (lane & 3) << 2;     // feature start within slice
  const int gnode = base + nl;
#pragma unroll
  for (int jt = 0; jt < 8; ++jt) {
    if (gnode < n) {
      ushort4 v = *reinterpret_cast<const ushort4*>(&ep[nl * 132 + jt * 16 + f4]);
      *reinterpret_cast<ushort4*>(&ht[((size_t)jt * n + gnode) * 16 + f4]) = v;
    }
  }
}

// ---------------- k2: coarse bucket histogram (bucket = row >> BSHIFT) ----------------
__global__ __launch_bounds__(256) void bucket_hist_kernel(
    const int* __restrict__ row, int* __restrict__ bhist, int e_total, int nb) {
  __shared__ int bh[MAXB];
  const int t = threadIdx.x;
  bh[t] = 0;
  __syncthreads();
  int i = blockIdx.x * 256 + t;
  const int stride = gridDim.x * 256;
  for (; i < e_total; i += stride) atomicAdd(&bh[row[i] >> BSHIFT], 1);
  __syncthreads();
  if (t < nb) {
    int c = bh[t];
    if (c) atomicAdd(&bhist[t], c);
  }
}

// ---------------- k3: exclusive scan of bucket hist -> bbase, bcursor ----------------
__global__ void bucket_scan_kernel(const int* __restrict__ bhist, int* __restrict__ bbase,
                                   int* __restrict__ bcursor, int nb, int e_total) {
  __shared__ int sd[MAXB];
  const int t = threadIdx.x;  // MAXB
  int v = (t < nb) ? bhist[t] : 0;
  sd[t] = v;
  __syncthreads();
  for (int off = 1; off < MAXB; off <<= 1) {
    int u = (t >= off) ? sd[t - off] : 0;
    __syncthreads();
    sd[t] += u;
    __syncthreads();
  }
  int excl = sd[t] - v;
  if (t < nb) { bbase[t] = excl; bcursor[t] = excl; }
  if (t == 0) bbase[nb] = e_total;
}

// ---------------- k4: bin edges into coarse buckets, packed (lr<<17)|col ----------------
__global__ __launch_bounds__(256) void bin_kernel(
    const int* __restrict__ row, const int* __restrict__ col,
    int* __restrict__ bcursor, unsigned int* __restrict__ pairs, int e_total, int nb) {
  __shared__ int scount[MAXB];
  __shared__ int gbase[MAXB];
  const int t = threadIdx.x;
  scount[t] = 0;
  __syncthreads();
  const int base = blockIdx.x * BIN_CHUNK;
  int bkt[BIN_EPT], slot[BIN_EPT];
  unsigned int pk[BIN_EPT];
#pragma unroll
  for (int k = 0; k < BIN_EPT; ++k) {
    int i = base + t + (k << 8);
    bkt[k] = -1;
    if (i < e_total) {
      int r = row[i], c = col[i];
      bkt[k] = r >> BSHIFT;
      pk[k] = ((unsigned int)(r & ((1 << BSHIFT) - 1)) << 17) | (unsigned int)c;
      slot[k] = atomicAdd(&scount[bkt[k]], 1);
    }
  }
  __syncthreads();
  if (t < nb) {
    int c = scount[t];
    gbase[t] = c ? atomicAdd(&bcursor[t], c) : 0;
  }
  __syncthreads();
#pragma unroll
  for (int k = 0; k < BIN_EPT; ++k) {
    if (bkt[k] >= 0) pairs[gbase[bkt[k]] + slot[k]] = pk[k];
  }
}

// ---------------- k5: per-bucket CSR build (rowptr + scol), L2-local ----------------
__global__ __launch_bounds__(256) void csr_kernel(
    const unsigned int* __restrict__ pairs, const int* __restrict__ bbase,
    int* __restrict__ rowptr, int* __restrict__ scol, int n, int e_total) {
  __shared__ int lh[1 << BSHIFT];
  __shared__ int sscan[256];
  const int b = blockIdx.x;
  const int t = threadIdx.x;
  const int node_base = b << BSHIFT;
  const int nn = min(1 << BSHIFT, n - node_base);
  const int p0 = bbase[b], p1 = bbase[b + 1];
  for (int j = t; j < (1 << BSHIFT); j += 256) lh[j] = 0;
  __syncthreads();
  for (int i = p0 + t; i < p1; i += 256) {
    atomicAdd(&lh[pairs[i] >> 17], 1);
  }
  __syncthreads();
  const int v0 = lh[2 * t + 0], v1 = lh[2 * t + 1];
  const int s = v0 + v1;
  sscan[t] = s;
  __syncthreads();
  for (int off = 1; off < 256; off <<= 1) {
    int u = (t >= off) ? sscan[t - off] : 0;
    __syncthreads();
    sscan[t] += u;
    __syncthreads();
  }
  const int excl = sscan[t] - s;
  const int c0 = excl, c1 = excl + v0;
  if (2 * t + 0 < nn) rowptr[node_base + 2 * t + 0] = p0 + c0;
  if (2 * t + 1 < nn) rowptr[node_base + 2 * t + 1] = p0 + c1;
  __syncthreads();
  lh[2 * t + 0] = c0; lh[2 * t + 1] = c1;
  __syncthreads();
  for (int i = p0 + t; i < p1; i += 256) {
    unsigned int p = pairs[i];
    int pl = atomicAdd(&lh[p >> 17], 1);
    scol[p0 + pl] = (int)(p & 0x1FFFFu);
  }
  if (b == 0 && t == 0) rowptr[n] = e_total;
}

// ---------------- k6: feature-sliced mean-agg; slice = blockIdx & 7 -> XCD affinity ----------
// 8-lane group per node (f = lane&7 covers 16 feats), 32 nodes per block pass; NO shuffles —
// each lane serially accumulates its node's edges in registers; rowptr/scol broadcast in group.
__global__ __launch_bounds__(256) void agg_kernel(
    const ushort2* __restrict__ ht2, const int* __restrict__ rowptr,
    const int* __restrict__ scol, unsigned short* __restrict__ outp,
    float* __restrict__ stat_sum, float* __restrict__ stat_sumsq, int n, int npp) {
  const int t = threadIdx.x;
  const int s = blockIdx.x & 7;
  const int part = blockIdx.x >> 3;
  const int f = t & 7;          // feature pair within slice
  const int nsub = t >> 3;      // 0..31: node offset within pass
  const size_t sn = (size_t)s * n;
  const int start = part * npp;
  const int end = min(n, start + npp);
  ushort2* op2 = reinterpret_cast<ushort2*>(outp);
  float ls0 = 0.f, ls1 = 0.f, lq0 = 0.f, lq1 = 0.f;
  for (int node = start + nsub; node < end; node += 32) {
    const int r0 = rowptr[node], r1 = rowptr[node + 1];
    float a0 = 0.f, a1 = 0.f;
    int e = r0;
    for (; e + 1 < r1; e += 2) {
      int c0 = scol[e], c1 = scol[e + 1];
      ushort2 v0 = ht2[(sn + c0) * 8 + f];
      ushort2 v1 = ht2[(sn + c1) * 8 + f];
      a0 += bf2f(v0.x) + bf2f(v1.x);
      a1 += bf2f(v0.y) + bf2f(v1.y);
    }
    if (e < r1) {
      int c0 = scol[e];
      ushort2 v0 = ht2[(sn + c0) * 8 + f];
      a0 += bf2f(v0.x); a1 += bf2f(v0.y);
    }
    ushort2 hv = ht2[(sn + node) * 8 + f];
    const float inv = 1.0f / ((float)(r1 - r0) + 1e-8f);
    float v0 = fmaf(a0, inv, bf2f(hv.x));
    float v1 = fmaf(a1, inv, bf2f(hv.y));
    ushort2 o; o.x = f2bf(v0); o.y = f2bf(v1);
    op2[(sn + node) * 8 + f] = o;
    ls0 += v0; ls1 += v1;
    lq0 = fmaf(v0, v0, lq0); lq1 = fmaf(v1, v1, lq1);
  }
  __shared__ float rs[16], rq[16];
  if (t < 16) { rs[t] = 0.f; rq[t] = 0.f; }
  __syncthreads();
  atomicAdd(&rs[2 * f], ls0); atomicAdd(&rs[2 * f + 1], ls1);
  atomicAdd(&rq[2 * f], lq0); atomicAdd(&rq[2 * f + 1], lq1);
  __syncthreads();
  if (t < 16) {
    atomicAdd(&stat_sum[s * 16 + t], rs[t]);
    atomicAdd(&stat_sumsq[s * 16 + t], rq[t]);
  }
}

// ---------------- k7: BN stats -> per-feature scale/shift ----------------
__global__ void finalize_kernel(const float* __restrict__ ssum, const float* __restrict__ ssq,
                                const float* __restrict__ gamma, const float* __restrict__ beta,
                                float* __restrict__ scale, float* __restrict__ shift, int n) {
  const int t = threadIdx.x;  // 128
  const float invn = 1.0f / (float)n;
  float mean = ssum[t] * invn;
  float var = ssq[t] * invn - mean * mean;
  float sc = gamma[t] * rsqrtf(var + BN_EPS_F);
  scale[t] = sc;
  shift[t] = beta[t] - mean * sc;
}

// ---------------- k8: BN apply — read tiled bf16 pre-BN, write fp32 d_out rows ----------------
__global__ __launch_bounds__(256) void bn_kernel(const unsigned short* __restrict__ outp,
                                                 float* __restrict__ out,
                                                 const float* __restrict__ scale,
                                                 const float* __restrict__ shift, int n_nodes) {
  __shared__ float sc[128], sh[128];
  if (threadIdx.x < 128) {
    sc[threadIdx.x] = scale[threadIdx.x];
    sh[threadIdx.x] = shift[threadIdx.x];
  }
  __syncthreads();
  const ushort4* op4 = reinterpret_cast<const ushort4*>(outp);
  const int total4 = n_nodes * 32;
  int i = blockIdx.x * 256 + threadIdx.x;
  const int stride = gridDim.x * 256;
  float4* o4 = reinterpret_cast<float4*>(out);
  for (; i < total4; i += stride) {
    const int node = i >> 5, fq4 = i & 31;
    const int slice = fq4 >> 2;
    ushort4 v = op4[((size_t)slice * n_nodes + node) * 4 + (fq4 & 3)];
    const int fq = fq4 << 2;
    float4 r;
    r.x = fmaf(bf2f(v.x), sc[fq + 0], sh[fq + 0]);
    r.y = fmaf(bf2f(v.y), sc[fq + 1], sh[fq + 1]);
    r.z = fmaf(bf2f(v.z), sc[fq + 2], sh[fq + 2]);
    r.w = fmaf(bf2f(v.w), sc[fq + 3], sh[fq + 3]);
    o4[i] = r;
  }
}

extern "C" void kernel_launch(void* const* d_in, const int* in_sizes, int n_in,
                              void* d_out, int out_size, void* d_ws, size_t ws_size,
                              hipStream_t stream) {
  const float* x     = (const float*)d_in[0];
  const int*   ei    = (const int*)d_in[1];
  const float* W     = (const float*)d_in[2];
  const float* bias  = (const float*)d_in[3];
  const float* gamma = (const float*)d_in[4];
  const float* beta  = (const float*)d_in[5];
  const int n = in_sizes[0] / 128;   // 100000
  const int e = in_sizes[1] / 2;     // 1600000
  const int* row = ei;
  const int* col = ei + e;
  float* out = (float*)d_out;

  char* base = (char*)d_ws;
  size_t off = 0;
  auto carve = [&](size_t bytes) -> char* {
    char* p = base + off;
    off += (bytes + 255) & ~(size_t)255;
    return p;
  };
  unsigned short* ht   = (unsigned short*)carve((size_t)n * 128 * 2);  // 25.6 MB tiled h
  unsigned short* outp = (unsigned short*)carve((size_t)n * 128 * 2);  // 25.6 MB tiled pre-BN
  unsigned short* wfrag = (unsigned short*)carve(128 * 128 * 2);       // 32 KB
  unsigned int* pairs = (unsigned int*)carve((size_t)e * 4);           // 6.4 MB
  int*   scol     = (int*)carve((size_t)e * 4);                        // 6.4 MB
  int*   rowptr   = (int*)carve((size_t)(n + 1) * 4);
  int*   bcursor  = (int*)carve(MAXB * 4);
  int*   bbase    = (int*)carve((MAXB + 1) * 4);
  float* scale    = (float*)carve(512);
  float* shift    = (float*)carve(512);
  char*  zbase    = base + off;
  int*   bhist    = (int*)carve(MAXB * 4);
  float* ssum     = (float*)carve(512);
  float* ssq      = (float*)carve(512);
  size_t zlen     = (size_t)((base + off) - zbase);
  (void)ws_size; (void)n_in; (void)out_size;

  const int nb = (n + (1 << BSHIFT) - 1) >> BSHIFT;      // 196 (<= MAXB required)
  const int bin_grid = (e + BIN_CHUNK - 1) / BIN_CHUNK;  // 391
  const int lin_grid = (n + 63) / 64;                    // 1563
  const int npp = (n + NPART - 1) / NPART;               // 250

  hipMemsetAsync(zbase, 0, zlen, stream);
  wfrag_kernel<<<64, 256, 0, stream>>>(W, wfrag);
  linear_kernel<<<lin_grid, 256, 0, stream>>>(x, wfrag, bias, ht, n);
  bucket_hist_kernel<<<256, 256, 0, stream>>>(row, bhist, e, nb);
  bucket_scan_kernel<<<1, MAXB, 0, stream>>>(bhist, bbase, bcursor, nb, e);
  bin_kernel<<<bin_grid, 256, 0, stream>>>(row, col, bcursor, pairs, e, nb);
  csr_kernel<<<nb, 256, 0, stream>>>(pairs, bbase, rowptr, scol, n, e);
  agg_kernel<<<8 * NPART, 256, 0, stream>>>((const ushort2*)ht, rowptr, scol, outp, ssum, ssq, n, npp);
  finalize_kernel<<<1, 128, 0, stream>>>(ssum, ssq, gamma, beta, scale, shift, n);
  bn_kernel<<<2048, 256, 0, stream>>>(outp, out, scale, shift, n);
}